// Round 1
// baseline (1129.092 us; speedup 1.0000x reference)
//
#include <hip/hip_runtime.h>
#include <stdint.h>

// Problem constants (from reference)
#define O_DIM 4096
#define I_DIM 4096
#define NB_DIM 128
#define R_DIM 16
#define M_DIM 16384          // B*S = 8*2048
#define LORA_SCALE 0.5f
#define Q_ZERO 128.0f

typedef short bf16x8 __attribute__((ext_vector_type(8)));
typedef float f32x4 __attribute__((ext_vector_type(4)));

__device__ __forceinline__ uint16_t f2bf(float f) {
    union { float f; uint32_t u; } v; v.f = f;
    uint32_t u = v.u;
    return (uint16_t)((u + 0x7fffu + ((u >> 16) & 1u)) >> 16);   // RNE
}

__device__ __forceinline__ void gll16(const void* g, void* l) {
    __builtin_amdgcn_global_load_lds(
        (const __attribute__((address_space(1))) void*)g,
        (__attribute__((address_space(3))) void*)l, 16, 0, 0);
}

// ---------------------------------------------------------------------------
// Kernel 1: W = scales * (q - 128) + 0.5 * up @ down  -> bf16 [O, I]
// one thread per 4 consecutive i of one o-row
// ---------------------------------------------------------------------------
__global__ void build_w_kernel(const int* __restrict__ qw,
                               const float* __restrict__ scales,
                               const float* __restrict__ up,
                               const float* __restrict__ down,
                               uint16_t* __restrict__ wout) {
    int idx = blockIdx.x * 256 + threadIdx.x;       // [0, O*I/4)
    int i4  = idx & (I_DIM / 4 - 1);                // I/4 = 1024
    int o   = idx >> 10;
    int4 q = ((const int4*)qw)[(size_t)o * (I_DIM / 4) + i4];
    float scale = scales[o * NB_DIM + (i4 >> 3)];   // block = (i4*4)/32
    float a0 = 0.f, a1 = 0.f, a2 = 0.f, a3 = 0.f;
#pragma unroll
    for (int r = 0; r < R_DIM; ++r) {
        float u = up[o * R_DIM + r];
        float4 d = ((const float4*)down)[r * (I_DIM / 4) + i4];
        a0 += u * d.x; a1 += u * d.y; a2 += u * d.z; a3 += u * d.w;
    }
    float w0 = scale * ((float)q.x - Q_ZERO) + LORA_SCALE * a0;
    float w1 = scale * ((float)q.y - Q_ZERO) + LORA_SCALE * a1;
    float w2 = scale * ((float)q.z - Q_ZERO) + LORA_SCALE * a2;
    float w3 = scale * ((float)q.w - Q_ZERO) + LORA_SCALE * a3;
    ushort4 outv = { f2bf(w0), f2bf(w1), f2bf(w2), f2bf(w3) };
    ((ushort4*)wout)[(size_t)o * (I_DIM / 4) + i4] = outv;
}

// ---------------------------------------------------------------------------
// Kernel 2: x f32 -> bf16, 8 elems/thread
// ---------------------------------------------------------------------------
__global__ void cvt_x_kernel(const float* __restrict__ x,
                             uint16_t* __restrict__ xb) {
    size_t idx = (size_t)blockIdx.x * 256 + threadIdx.x;   // [0, M*I/8)
    float4 a = ((const float4*)x)[idx * 2];
    float4 b = ((const float4*)x)[idx * 2 + 1];
    ushort4 o0 = { f2bf(a.x), f2bf(a.y), f2bf(a.z), f2bf(a.w) };
    ushort4 o1 = { f2bf(b.x), f2bf(b.y), f2bf(b.z), f2bf(b.w) };
    ((ushort4*)xb)[idx * 2] = o0;
    ((ushort4*)xb)[idx * 2 + 1] = o1;
}

// ---------------------------------------------------------------------------
// Kernel 3: GEMM  out[m][n] = sum_k A[m][k] * W[n][k] + bias[n]
// m97 structure: 128x128 tile, BK=32, 4 waves, 4x4 acc of 16x16x32 bf16 MFMA,
// global_load_lds width=16 staging.
// A_BF16: A comes pre-converted from ws (DMA path). Else: f32 load + cvt.
// ---------------------------------------------------------------------------
template <bool A_BF16>
__global__ void gemm_kernel(const uint16_t* __restrict__ Ab,
                            const float* __restrict__ Af,
                            const uint16_t* __restrict__ Wb,
                            const float* __restrict__ bias,
                            float* __restrict__ out) {
    __shared__ __align__(16) uint16_t As[128 * 32];
    __shared__ __align__(16) uint16_t Bs[128 * 32];
    const int tid = threadIdx.x;
    const int wave = tid >> 6, lane = tid & 63;
    const int m0 = blockIdx.y * 128;
    const int n0 = blockIdx.x * 128;
    const int wr = wave >> 1, wc = wave & 1;     // wave's 64x64 sub-tile

    f32x4 acc[4][4] = {};

    const int lrow = lane & 15;
    const int lk = (lane >> 4) * 8;

    for (int k0 = 0; k0 < I_DIM; k0 += 32) {
        // ---- stage A tile [128 x 32] ----
        if (A_BF16) {
#pragma unroll
            for (int j = 0; j < 2; ++j) {
                int slot = wave * 2 + j;                 // 0..7, 16 rows each
                int row = slot * 16 + (lane >> 2);
                int col = (lane & 3) * 8;
                gll16(Ab + (size_t)(m0 + row) * I_DIM + k0 + col,
                      As + slot * 512);
            }
        } else {
            int row = tid >> 1;
            int col0 = (tid & 1) * 16;
            const float4* gp =
                (const float4*)(Af + (size_t)(m0 + row) * I_DIM + k0 + col0);
            float4 v0 = gp[0], v1 = gp[1], v2 = gp[2], v3 = gp[3];
            ushort4* dst = (ushort4*)&As[row * 32 + col0];
            ushort4 s0 = { f2bf(v0.x), f2bf(v0.y), f2bf(v0.z), f2bf(v0.w) };
            ushort4 s1 = { f2bf(v1.x), f2bf(v1.y), f2bf(v1.z), f2bf(v1.w) };
            ushort4 s2 = { f2bf(v2.x), f2bf(v2.y), f2bf(v2.z), f2bf(v2.w) };
            ushort4 s3 = { f2bf(v3.x), f2bf(v3.y), f2bf(v3.z), f2bf(v3.w) };
            dst[0] = s0; dst[1] = s1; dst[2] = s2; dst[3] = s3;
        }
        // ---- stage B tile [128 x 32] via DMA ----
#pragma unroll
        for (int j = 0; j < 2; ++j) {
            int slot = wave * 2 + j;
            int row = slot * 16 + (lane >> 2);
            int col = (lane & 3) * 8;
            gll16(Wb + (size_t)(n0 + row) * I_DIM + k0 + col,
                  Bs + slot * 512);
        }
        __syncthreads();

        // ---- compute: 8 ds_read_b128 + 16 MFMA ----
        bf16x8 a[4], b[4];
#pragma unroll
        for (int mi = 0; mi < 4; ++mi)
            a[mi] = *(const bf16x8*)&As[(wr * 64 + mi * 16 + lrow) * 32 + lk];
#pragma unroll
        for (int ni = 0; ni < 4; ++ni)
            b[ni] = *(const bf16x8*)&Bs[(wc * 64 + ni * 16 + lrow) * 32 + lk];
#pragma unroll
        for (int mi = 0; mi < 4; ++mi)
#pragma unroll
            for (int ni = 0; ni < 4; ++ni)
                acc[mi][ni] = __builtin_amdgcn_mfma_f32_16x16x32_bf16(
                    a[mi], b[ni], acc[mi][ni], 0, 0, 0);
        __syncthreads();
    }

    // ---- epilogue: C/D layout col=lane&15, row=(lane>>4)*4+r ----
    const int lcol = lane & 15;
    const int lquad = lane >> 4;
#pragma unroll
    for (int ni = 0; ni < 4; ++ni) {
        int n = n0 + wc * 64 + ni * 16 + lcol;
        float bv = bias[n];
#pragma unroll
        for (int mi = 0; mi < 4; ++mi) {
            int mbase = m0 + wr * 64 + mi * 16 + lquad * 4;
#pragma unroll
            for (int r = 0; r < 4; ++r)
                out[(size_t)(mbase + r) * O_DIM + n] = acc[mi][ni][r] + bv;
        }
    }
}

// ---------------------------------------------------------------------------
extern "C" void kernel_launch(void* const* d_in, const int* in_sizes, int n_in,
                              void* d_out, int out_size, void* d_ws,
                              size_t ws_size, hipStream_t stream) {
    const int* qweight = (const int*)d_in[0];
    const float* scales = (const float*)d_in[1];
    const float* lora_up = (const float*)d_in[2];
    const float* lora_down = (const float*)d_in[3];
    const float* bias = (const float*)d_in[4];
    const float* x = (const float*)d_in[5];
    float* out = (float*)d_out;

    uint16_t* w_bf16 = (uint16_t*)d_ws;
    const size_t w_bytes = (size_t)O_DIM * I_DIM * 2;          // 32 MiB
    uint16_t* x_bf16 = (uint16_t*)((char*)d_ws + w_bytes);
    const size_t need_full = w_bytes + (size_t)M_DIM * I_DIM * 2;  // 160 MiB

    build_w_kernel<<<O_DIM * I_DIM / 4 / 256, 256, 0, stream>>>(
        qweight, scales, lora_up, lora_down, w_bf16);

    dim3 grid(O_DIM / 128, M_DIM / 128);
    if (ws_size >= need_full) {
        cvt_x_kernel<<<(size_t)M_DIM * I_DIM / 8 / 256, 256, 0, stream>>>(
            x, x_bf16);
        gemm_kernel<true><<<grid, 256, 0, stream>>>(
            x_bf16, nullptr, w_bf16, bias, out);
    } else {
        gemm_kernel<false><<<grid, 256, 0, stream>>>(
            nullptr, x, w_bf16, bias, out);
    }
}